// Round 1
// baseline (403.004 us; speedup 1.0000x reference)
//
#include <hip/hip_runtime.h>

// MultiBoxLoss (SSD) for B=128, P=8732, C=21, N=16 (all derived at runtime).
// K1: per-batch matching + loc loss (1 block/batch, match state in LDS)
// K2: per-prior cross-entropy (memory-bound pass over 94MB scores)
// K3: per-batch exact top-k via binary search on float bits (LDS-resident)
// K4: final scalar combine.
// ws layout: [B*P floats: labels(int) then overwritten by conf_neg] [B ints n_pos] [4 words acc]
// acc[0]=loc_sl1_sum(f32) acc[1]=conf_pos_sum(f32) acc[2]=conf_hard_neg_sum(f32) acc[3]=n_pos_total(i32)

#define MAXN 16

__device__ __forceinline__ float sl1f(float d) {
    float ad = fabsf(d);
    return ad < 1.0f ? 0.5f * d * d : ad - 0.5f;
}

__global__ __launch_bounds__(256) void k_match(
    const float* __restrict__ plocs,   // [B,P,4]
    const float* __restrict__ boxes,   // [B,N,4] xy
    const int*   __restrict__ labels,  // [B,N]
    const float* __restrict__ priors,  // [P,4] cxcy
    int P, int N,
    int*   __restrict__ cls_out,       // [B,P] (slot, as int)
    int*   __restrict__ npos_out,      // [B]
    float* __restrict__ acc)
{
    extern __shared__ unsigned char smem[];
    float* ovl = (float*)smem;                       // P floats
    unsigned short* obj = (unsigned short*)(ovl + P); // P u16

    __shared__ float sx1[MAXN], sy1[MAXN], sx2[MAXN], sy2[MAXN], barea[MAXN];
    __shared__ int   blab[MAXN], pfo[MAXN];
    __shared__ float rv[4 * MAXN];
    __shared__ int   ri[4 * MAXN];
    __shared__ float redf[4];
    __shared__ int   redi[4];

    const int b = blockIdx.x;
    const int tid = threadIdx.x;
    const int lane = tid & 63, wid = tid >> 6;
    if (N > MAXN) N = MAXN;  // safety clamp (N==16 for this problem)

    if (tid < N) {
        const float* bp = boxes + ((size_t)b * N + tid) * 4;
        float x1 = bp[0], y1 = bp[1], x2 = bp[2], y2 = bp[3];
        sx1[tid] = x1; sy1[tid] = y1; sx2[tid] = x2; sy2[tid] = y2;
        barea[tid] = (x2 - x1) * (y2 - y1);
        blab[tid] = labels[(size_t)b * N + tid];
    }
    __syncthreads();

    // Phase 1: per-prior best object (first-index ties) + per-thread per-object best prior
    float bv[MAXN]; int bi[MAXN];
#pragma unroll
    for (int n = 0; n < MAXN; n++) { bv[n] = -1.0f; bi[n] = 0x7fffffff; }

    for (int p = tid; p < P; p += 256) {
        float4 pr = ((const float4*)priors)[p];
        float px1 = pr.x - pr.z * 0.5f, py1 = pr.y - pr.w * 0.5f;
        float px2 = pr.x + pr.z * 0.5f, py2 = pr.y + pr.w * 0.5f;
        float parea = (px2 - px1) * (py2 - py1);
        float best = -1.0f; int bestn = 0;
#pragma unroll
        for (int n = 0; n < MAXN; n++) {
            if (n < N) {
                float iw = fmaxf(fminf(sx2[n], px2) - fmaxf(sx1[n], px1), 0.0f);
                float ih = fmaxf(fminf(sy2[n], py2) - fmaxf(sy1[n], py1), 0.0f);
                float inter = iw * ih;
                float iou = inter / (barea[n] + parea - inter);
                if (iou > best) { best = iou; bestn = n; }     // strict >: first index wins
                if (iou > bv[n]) { bv[n] = iou; bi[n] = p; }   // ascending p: first index wins
            }
        }
        ovl[p] = best;
        obj[p] = (unsigned short)bestn;
    }

    // Phase 2: reduce per-object argmax across threads (tiebreak: min prior index)
#pragma unroll
    for (int n = 0; n < MAXN; n++) {
        float v = bv[n]; int i = bi[n];
#pragma unroll
        for (int off = 32; off > 0; off >>= 1) {
            float ov = __shfl_down(v, off);
            int   oi = __shfl_down(i, off);
            if (ov > v || (ov == v && oi < i)) { v = ov; i = oi; }
        }
        if (lane == 0) { rv[wid * MAXN + n] = v; ri[wid * MAXN + n] = i; }
    }
    __syncthreads();
    if (tid < N) {
        float v = rv[tid]; int i = ri[tid];
        for (int w = 1; w < 4; w++) {
            float ov = rv[w * MAXN + tid]; int oi = ri[w * MAXN + tid];
            if (ov > v || (ov == v && oi < i)) { v = ov; i = oi; }
        }
        pfo[tid] = i;
    }
    __syncthreads();
    // Phase 3: sequential override (last-wins, matches XLA scatter order)
    if (tid == 0) {
        for (int n = 0; n < N; n++) {
            int p = pfo[n];
            obj[p] = (unsigned short)n;
            ovl[p] = 1.0f;
        }
    }
    __syncthreads();

    // Phase 4: labels, encode, SmoothL1, n_pos
    float locs = 0.0f; int np = 0;
    for (int p = tid; p < P; p += 256) {
        int n = obj[p];
        float ov = ovl[p];
        int lab = (ov < 0.5f) ? 0 : blab[n];
        cls_out[(size_t)b * P + p] = lab;
        if (lab != 0) {
            np++;
            float4 pr = ((const float4*)priors)[p];
            float cx = (sx1[n] + sx2[n]) * 0.5f, cy = (sy1[n] + sy2[n]) * 0.5f;
            float w = sx2[n] - sx1[n], h = sy2[n] - sy1[n];
            float g0 = (cx - pr.x) / (pr.z / 10.0f);
            float g1 = (cy - pr.y) / (pr.w / 10.0f);
            float g2 = logf(w / pr.z) * 5.0f;
            float g3 = logf(h / pr.w) * 5.0f;
            float4 pl = ((const float4*)plocs)[(size_t)b * P + p];
            locs += sl1f(pl.x - g0) + sl1f(pl.y - g1) + sl1f(pl.z - g2) + sl1f(pl.w - g3);
        }
    }
#pragma unroll
    for (int off = 32; off > 0; off >>= 1) {
        locs += __shfl_down(locs, off);
        np   += __shfl_down(np, off);
    }
    if (lane == 0) { redf[wid] = locs; redi[wid] = np; }
    __syncthreads();
    if (tid == 0) {
        float L = redf[0] + redf[1] + redf[2] + redf[3];
        int   c = redi[0] + redi[1] + redi[2] + redi[3];
        npos_out[b] = c;
        atomicAdd(&acc[0], L);
        atomicAdd((int*)(acc + 3), c);
    }
}

__global__ __launch_bounds__(256) void k_conf(
    const float* __restrict__ scores, // [B*P, C]
    int total, int C,
    float* __restrict__ slot,         // in: labels (int), out: conf_neg (float)
    float* __restrict__ acc)
{
    __shared__ float redf[4];
    int idx = blockIdx.x * 256 + threadIdx.x;
    int lane = threadIdx.x & 63, wid = threadIdx.x >> 6;
    float posc = 0.0f;
    if (idx < total) {
        int lab = ((const int*)slot)[idx];
        const float* __restrict__ s = scores + (size_t)idx * C;
        float m = -3.402823466e38f;
        for (int c = 0; c < C; c++) m = fmaxf(m, s[c]);
        float sum = 0.0f;
        for (int c = 0; c < C; c++) sum += __expf(s[c] - m);
        float conf = m + __logf(sum) - s[lab];   // -log_softmax[lab]
        if (lab != 0) { posc = conf; conf = 0.0f; }
        slot[idx] = conf;
    }
#pragma unroll
    for (int off = 32; off > 0; off >>= 1) posc += __shfl_down(posc, off);
    if (lane == 0) redf[wid] = posc;
    __syncthreads();
    if (threadIdx.x == 0) atomicAdd(&acc[1], redf[0] + redf[1] + redf[2] + redf[3]);
}

__global__ __launch_bounds__(256) void k_hard(
    const float* __restrict__ conf,  // [B,P] conf_neg (>=0; 0 at positives)
    const int* __restrict__ npos,
    int P,
    float* __restrict__ acc)
{
    extern __shared__ unsigned int u[];   // P uints
    __shared__ int   redi[4];
    __shared__ float redf[4];
    int b = blockIdx.x, tid = threadIdx.x;
    int lane = tid & 63, wid = tid >> 6;
    long long kk = (long long)npos[b] * 3;
    int k = kk > P ? P : (int)kk;
    if (k <= 0) return;  // block-uniform exit, no barriers crossed

    for (int p = tid; p < P; p += 256) u[p] = __float_as_uint(conf[(size_t)b * P + p]);
    __syncthreads();

    // largest bit-pattern t with count(x >= t) >= k  ==  exact k-th largest value
    unsigned lo = 0u, hi = 0x7F800000u;
    while (lo < hi) {
        unsigned mid = lo + ((hi - lo + 1) >> 1);
        int cnt = 0;
        for (int p = tid; p < P; p += 256) cnt += (u[p] >= mid) ? 1 : 0;
#pragma unroll
        for (int off = 32; off > 0; off >>= 1) cnt += __shfl_down(cnt, off);
        if (lane == 0) redi[wid] = cnt;
        __syncthreads();
        int c = redi[0] + redi[1] + redi[2] + redi[3];  // same in every thread
        __syncthreads();
        if (c >= k) lo = mid; else hi = mid - 1;
    }

    float t = __uint_as_float(lo);
    float sgt = 0.0f; int cgt = 0;
    for (int p = tid; p < P; p += 256) {
        float v = __uint_as_float(u[p]);
        if (v > t) { sgt += v; cgt++; }
    }
#pragma unroll
    for (int off = 32; off > 0; off >>= 1) {
        sgt += __shfl_down(sgt, off);
        cgt += __shfl_down(cgt, off);
    }
    if (lane == 0) { redf[wid] = sgt; redi[wid] = cgt; }
    __syncthreads();
    if (tid == 0) {
        float S = redf[0] + redf[1] + redf[2] + redf[3];
        int  Cg = redi[0] + redi[1] + redi[2] + redi[3];
        atomicAdd(&acc[2], S + (float)(k - Cg) * t);  // ties at t handled exactly
    }
}

__global__ void k_final(const float* __restrict__ acc, float* __restrict__ out)
{
    float npos = (float)((const int*)acc)[3];
    out[0] = (acc[2] + acc[1]) / npos + acc[0] / (npos * 4.0f);
}

extern "C" void kernel_launch(void* const* d_in, const int* in_sizes, int n_in,
                              void* d_out, int out_size, void* d_ws, size_t ws_size,
                              hipStream_t stream)
{
    const float* plocs  = (const float*)d_in[0];
    const float* scores = (const float*)d_in[1];
    const float* boxes  = (const float*)d_in[2];
    const int*   labels = (const int*)d_in[3];
    const float* priors = (const float*)d_in[4];

    int P = in_sizes[4] / 4;
    int B = in_sizes[0] / (P * 4);
    int C = in_sizes[1] / (in_sizes[0] / 4);
    int N = in_sizes[3] / B;

    float* slot = (float*)d_ws;                                       // B*P floats
    int*   npos = (int*)((char*)d_ws + (size_t)B * P * sizeof(float)); // B ints
    float* acc  = (float*)((char*)npos + (size_t)B * sizeof(int));     // 4 words

    hipMemsetAsync(acc, 0, 4 * sizeof(float), stream);

    size_t sm1 = (size_t)P * sizeof(float) + (size_t)P * sizeof(unsigned short);
    k_match<<<B, 256, sm1, stream>>>(plocs, boxes, labels, priors, P, N,
                                     (int*)slot, npos, acc);

    int total = B * P;
    k_conf<<<(total + 255) / 256, 256, 0, stream>>>(scores, total, C, slot, acc);

    k_hard<<<B, 256, (size_t)P * sizeof(unsigned int), stream>>>(slot, npos, P, acc);

    k_final<<<1, 1, 0, stream>>>(acc, (float*)d_out);
}

// Round 2
// 294.621 us; speedup vs baseline: 1.3679x; 1.3679x over previous
//
#include <hip/hip_runtime.h>

// MultiBoxLoss (SSD). B=128, P=8732, C=21, N=16 (runtime-derived).
// K1 k_match: per-batch matching + loc loss partials (1 block/batch, 1024 thr)
// K2 k_conf : per-prior CE, LDS-staged coalesced score reads (the 94MB pass)
// K3 k_hard : per-batch exact top-k via binary search on float bits (1024 thr)
// K4 k_final: sum partials, write scalar.
// ws: slot[B*P] f32 (labels -> conf_neg), npos[B] i32, locsum[B] f32,
//     hardsum[B] f32, possum[nconf] f32.

#define MAXN 16

__device__ __forceinline__ float sl1f(float d) {
    float ad = fabsf(d);
    return ad < 1.0f ? 0.5f * d * d : ad - 0.5f;
}

__global__ __launch_bounds__(1024) void k_match(
    const float* __restrict__ plocs,   // [B,P,4]
    const float* __restrict__ boxes,   // [B,N,4] xy
    const int*   __restrict__ labels,  // [B,N]
    const float* __restrict__ priors,  // [P,4] cxcy
    int P, int N,
    int*   __restrict__ cls_out,       // [B,P]
    int*   __restrict__ npos_out,      // [B]
    float* __restrict__ locsum)        // [B]
{
    extern __shared__ unsigned char smem[];
    float* ovl = (float*)smem;                        // P floats
    unsigned short* obj = (unsigned short*)(ovl + P); // P u16

    __shared__ float sx1[MAXN], sy1[MAXN], sx2[MAXN], sy2[MAXN], barea[MAXN];
    __shared__ int   blab[MAXN], pfo[MAXN];
    __shared__ float rv[16 * MAXN];
    __shared__ int   ri[16 * MAXN];
    __shared__ float redf[16];
    __shared__ int   redi[16];

    const int b = blockIdx.x;
    const int tid = threadIdx.x;
    const int lane = tid & 63, wid = tid >> 6;
    const int nthr = blockDim.x, nw = nthr >> 6;
    if (N > MAXN) N = MAXN;

    if (tid < N) {
        const float* bp = boxes + ((size_t)b * N + tid) * 4;
        float x1 = bp[0], y1 = bp[1], x2 = bp[2], y2 = bp[3];
        sx1[tid] = x1; sy1[tid] = y1; sx2[tid] = x2; sy2[tid] = y2;
        barea[tid] = (x2 - x1) * (y2 - y1);
        blab[tid] = labels[(size_t)b * N + tid];
    }
    __syncthreads();

    // Phase 1: per-prior best object (strict > => first-index ties, matches argmax)
    float bv[MAXN]; int bi[MAXN];
#pragma unroll
    for (int n = 0; n < MAXN; n++) { bv[n] = -1.0f; bi[n] = 0x7fffffff; }

    for (int p = tid; p < P; p += nthr) {
        float4 pr = ((const float4*)priors)[p];
        float px1 = pr.x - pr.z * 0.5f, py1 = pr.y - pr.w * 0.5f;
        float px2 = pr.x + pr.z * 0.5f, py2 = pr.y + pr.w * 0.5f;
        float parea = (px2 - px1) * (py2 - py1);
        float best = -1.0f; int bestn = 0;
#pragma unroll
        for (int n = 0; n < MAXN; n++) {
            if (n < N) {
                float iw = fmaxf(fminf(sx2[n], px2) - fmaxf(sx1[n], px1), 0.0f);
                float ih = fmaxf(fminf(sy2[n], py2) - fmaxf(sy1[n], py1), 0.0f);
                float inter = iw * ih;
                float iou = inter / (barea[n] + parea - inter);
                if (iou > best) { best = iou; bestn = n; }
                if (iou > bv[n]) { bv[n] = iou; bi[n] = p; }  // ascending p: first idx
            }
        }
        ovl[p] = best;
        obj[p] = (unsigned short)bestn;
    }

    // Phase 2: per-object argmax over priors (tiebreak min prior index)
#pragma unroll
    for (int n = 0; n < MAXN; n++) {
        float v = bv[n]; int i = bi[n];
#pragma unroll
        for (int off = 32; off > 0; off >>= 1) {
            float ov = __shfl_down(v, off);
            int   oi = __shfl_down(i, off);
            if (ov > v || (ov == v && oi < i)) { v = ov; i = oi; }
        }
        if (lane == 0) { rv[wid * MAXN + n] = v; ri[wid * MAXN + n] = i; }
    }
    __syncthreads();
    if (tid < N) {
        float v = rv[tid]; int i = ri[tid];
        for (int w = 1; w < nw; w++) {
            float ov = rv[w * MAXN + tid]; int oi = ri[w * MAXN + tid];
            if (ov > v || (ov == v && oi < i)) { v = ov; i = oi; }
        }
        pfo[tid] = i;
    }
    __syncthreads();
    // Phase 3: sequential override (last-wins scatter order)
    if (tid == 0) {
        for (int n = 0; n < N; n++) {
            int p = pfo[n];
            obj[p] = (unsigned short)n;
            ovl[p] = 1.0f;
        }
    }
    __syncthreads();

    // Phase 4: labels, gcxgcy encode, SmoothL1, n_pos
    float locs = 0.0f; int np = 0;
    for (int p = tid; p < P; p += nthr) {
        int n = obj[p];
        float ov = ovl[p];
        int lab = (ov < 0.5f) ? 0 : blab[n];
        cls_out[(size_t)b * P + p] = lab;
        if (lab != 0) {
            np++;
            float4 pr = ((const float4*)priors)[p];
            float cx = (sx1[n] + sx2[n]) * 0.5f, cy = (sy1[n] + sy2[n]) * 0.5f;
            float w = sx2[n] - sx1[n], h = sy2[n] - sy1[n];
            float g0 = (cx - pr.x) / (pr.z / 10.0f);
            float g1 = (cy - pr.y) / (pr.w / 10.0f);
            float g2 = logf(w / pr.z) * 5.0f;
            float g3 = logf(h / pr.w) * 5.0f;
            float4 pl = ((const float4*)plocs)[(size_t)b * P + p];
            locs += sl1f(pl.x - g0) + sl1f(pl.y - g1) + sl1f(pl.z - g2) + sl1f(pl.w - g3);
        }
    }
#pragma unroll
    for (int off = 32; off > 0; off >>= 1) {
        locs += __shfl_down(locs, off);
        np   += __shfl_down(np, off);
    }
    if (lane == 0) { redf[wid] = locs; redi[wid] = np; }
    __syncthreads();
    if (tid == 0) {
        float L = 0.0f; int c = 0;
        for (int w = 0; w < nw; w++) { L += redf[w]; c += redi[w]; }
        npos_out[b] = c;
        locsum[b] = L;
    }
}

__global__ __launch_bounds__(256) void k_conf(
    const float* __restrict__ scores, // [total, C]
    int total, int C,
    float* __restrict__ slot,         // in: labels(int), out: conf_neg(float)
    float* __restrict__ possum)       // [gridDim.x]
{
    extern __shared__ float sh[];     // 256*C floats
    __shared__ float redf[4];
    const int tid = threadIdx.x;
    const int lane = tid & 63, wid = tid >> 6;
    const int blk = blockIdx.x;
    const int row0 = blk * 256;

    // Stage 256 rows (256*C floats) coalesced as float4.
    // Assumes total*C divisible by 4 (B*P*C with B mult of 4) and row0*C%4==0.
    const size_t f4base = (size_t)row0 * C / 4;
    const size_t f4total = (size_t)total * C / 4;
    const int f4blk = 64 * C;  // 256*C/4
    const float4* __restrict__ s4 = (const float4*)scores;
    for (int j = tid; j < f4blk; j += 256) {
        size_t g = f4base + j;
        if (g < f4total) ((float4*)sh)[j] = s4[g];
    }
    __syncthreads();

    const int idx = row0 + tid;
    float posc = 0.0f;
    if (idx < total) {
        int lab = ((const int*)slot)[idx];
        const float* r = sh + tid * C;
        float m = -3.402823466e38f;
        for (int c = 0; c < C; c++) m = fmaxf(m, r[c]);
        float sum = 0.0f;
        for (int c = 0; c < C; c++) sum += __expf(r[c] - m);
        float conf = m + __logf(sum) - r[lab];   // -log_softmax[lab]
        if (lab != 0) { posc = conf; conf = 0.0f; }
        slot[idx] = conf;
    }
#pragma unroll
    for (int off = 32; off > 0; off >>= 1) posc += __shfl_down(posc, off);
    if (lane == 0) redf[wid] = posc;
    __syncthreads();
    if (tid == 0) possum[blk] = redf[0] + redf[1] + redf[2] + redf[3];
}

__global__ __launch_bounds__(1024) void k_hard(
    const float* __restrict__ conf,  // [B,P] conf_neg (>=0; 0 at positives)
    const int* __restrict__ npos,
    int P,
    float* __restrict__ hardsum)     // [B]
{
    extern __shared__ unsigned int u[];   // P uints
    __shared__ int   redi[16];
    __shared__ float redf[16];
    const int b = blockIdx.x, tid = threadIdx.x;
    const int lane = tid & 63, wid = tid >> 6;
    const int nthr = blockDim.x, nw = nthr >> 6;
    long long kk = (long long)npos[b] * 3;
    int k = kk > P ? P : (int)kk;
    if (k <= 0) {                       // block-uniform; must still write partial
        if (tid == 0) hardsum[b] = 0.0f;
        return;
    }

    for (int p = tid; p < P; p += nthr) u[p] = __float_as_uint(conf[(size_t)b * P + p]);
    __syncthreads();

    // largest bit pattern t with count(x >= t) >= k == exact k-th largest
    unsigned lo = 0u, hi = 0x7F800000u;
    while (lo < hi) {
        unsigned mid = lo + ((hi - lo + 1) >> 1);
        int cnt = 0;
        for (int p = tid; p < P; p += nthr) cnt += (u[p] >= mid) ? 1 : 0;
#pragma unroll
        for (int off = 32; off > 0; off >>= 1) cnt += __shfl_down(cnt, off);
        if (lane == 0) redi[wid] = cnt;
        __syncthreads();
        int c = 0;
        for (int w = 0; w < nw; w++) c += redi[w];   // broadcast reads, free
        __syncthreads();
        if (c >= k) lo = mid; else hi = mid - 1;
    }

    float t = __uint_as_float(lo);
    float sgt = 0.0f; int cgt = 0;
    for (int p = tid; p < P; p += nthr) {
        float v = __uint_as_float(u[p]);
        if (v > t) { sgt += v; cgt++; }
    }
#pragma unroll
    for (int off = 32; off > 0; off >>= 1) {
        sgt += __shfl_down(sgt, off);
        cgt += __shfl_down(cgt, off);
    }
    if (lane == 0) { redf[wid] = sgt; redi[wid] = cgt; }
    __syncthreads();
    if (tid == 0) {
        float S = 0.0f; int Cg = 0;
        for (int w = 0; w < nw; w++) { S += redf[w]; Cg += redi[w]; }
        hardsum[b] = S + (float)(k - Cg) * t;   // ties at t handled exactly
    }
}

__global__ __launch_bounds__(1024) void k_final(
    const int* __restrict__ npos, const float* __restrict__ locsum,
    const float* __restrict__ hardsum, const float* __restrict__ possum,
    int B, int nconf, float* __restrict__ out)
{
    const int tid = threadIdx.x, lane = tid & 63, wid = tid >> 6;
    __shared__ float rf[3 * 16];
    __shared__ int   ri[16];
    float lp = 0, pp = 0, hp = 0; int np = 0;
    for (int i = tid; i < B; i += 1024) { np += npos[i]; lp += locsum[i]; hp += hardsum[i]; }
    for (int i = tid; i < nconf; i += 1024) pp += possum[i];
#pragma unroll
    for (int off = 32; off > 0; off >>= 1) {
        np += __shfl_down(np, off); lp += __shfl_down(lp, off);
        pp += __shfl_down(pp, off); hp += __shfl_down(hp, off);
    }
    if (lane == 0) { ri[wid] = np; rf[wid] = lp; rf[16 + wid] = pp; rf[32 + wid] = hp; }
    __syncthreads();
    if (tid == 0) {
        int nw = (int)(blockDim.x >> 6);
        float L = 0, Pp = 0, H = 0; int Np = 0;
        for (int w = 0; w < nw; w++) { Np += ri[w]; L += rf[w]; Pp += rf[16 + w]; H += rf[32 + w]; }
        float npf = (float)Np;
        out[0] = (H + Pp) / npf + L / (npf * 4.0f);
    }
}

extern "C" void kernel_launch(void* const* d_in, const int* in_sizes, int n_in,
                              void* d_out, int out_size, void* d_ws, size_t ws_size,
                              hipStream_t stream)
{
    const float* plocs  = (const float*)d_in[0];
    const float* scores = (const float*)d_in[1];
    const float* boxes  = (const float*)d_in[2];
    const int*   labels = (const int*)d_in[3];
    const float* priors = (const float*)d_in[4];

    int P = in_sizes[4] / 4;
    int B = in_sizes[0] / (P * 4);
    int C = in_sizes[1] / (in_sizes[0] / 4);
    int N = in_sizes[3] / B;
    int total = B * P;
    int nconf = (total + 255) / 256;

    char* w = (char*)d_ws;
    float* slot    = (float*)w;                 w += (size_t)total * sizeof(float);
    int*   npos    = (int*)w;                   w += (size_t)B * sizeof(int);
    float* locsum  = (float*)w;                 w += (size_t)B * sizeof(float);
    float* hardsum = (float*)w;                 w += (size_t)B * sizeof(float);
    float* possum  = (float*)w;

    size_t sm1 = (size_t)P * (sizeof(float) + sizeof(unsigned short));
    k_match<<<B, 1024, sm1, stream>>>(plocs, boxes, labels, priors, P, N,
                                      (int*)slot, npos, locsum);

    size_t sm2 = (size_t)256 * C * sizeof(float);
    k_conf<<<nconf, 256, sm2, stream>>>(scores, total, C, slot, possum);

    k_hard<<<B, 1024, (size_t)P * sizeof(unsigned int), stream>>>(slot, npos, P, hardsum);

    k_final<<<1, 1024, 0, stream>>>(npos, locsum, hardsum, possum, B, nconf,
                                    (float*)d_out);
}

// Round 3
// 263.439 us; speedup vs baseline: 1.5298x; 1.1184x over previous
//
#include <hip/hip_runtime.h>

// MultiBoxLoss (SSD). B=128, P=8732, C=21, N=16 (runtime-derived).
// K1 k_match: per-batch matching + loc loss partials (1 block/batch).
//             Phase 1: per-prior argmax over objects (2 scalars/thread).
//             Phase 2: per-object argmax over priors, ONE WAVE PER OBJECT
//             (no per-thread arrays -> no scratch spill; round-2 version
//             spilled bv[16]/bi[16] = 295 MB of scratch traffic).
// K2 k_conf : per-prior CE, LDS-staged coalesced score reads (the 94MB pass)
// K3 k_hard : per-batch exact top-k, 4-ary search on float bits + ballot counts
// K4 k_final: sum partials, write scalar.
// ws: slot[B*P] f32 (labels -> conf_neg), npos[B] i32, locsum[B] f32,
//     hardsum[B] f32, possum[nconf] f32.

#define MAXN 16

__device__ __forceinline__ float sl1f(float d) {
    float ad = fabsf(d);
    return ad < 1.0f ? 0.5f * d * d : ad - 0.5f;
}

__global__ __launch_bounds__(1024) void k_match(
    const float* __restrict__ plocs,   // [B,P,4]
    const float* __restrict__ boxes,   // [B,N,4] xy
    const int*   __restrict__ labels,  // [B,N]
    const float* __restrict__ priors,  // [P,4] cxcy
    int P, int N,
    int*   __restrict__ cls_out,       // [B,P]
    int*   __restrict__ npos_out,      // [B]
    float* __restrict__ locsum)        // [B]
{
    extern __shared__ unsigned char smem[];
    float* ovl = (float*)smem;                        // P floats
    unsigned short* obj = (unsigned short*)(ovl + P); // P u16

    __shared__ float sx1[MAXN], sy1[MAXN], sx2[MAXN], sy2[MAXN], barea[MAXN];
    __shared__ int   blab[MAXN], pfo[MAXN];
    __shared__ float redf[16];
    __shared__ int   redi[16];

    const int b = blockIdx.x;
    const int tid = threadIdx.x;
    const int lane = tid & 63, wid = tid >> 6;
    const int nthr = blockDim.x, nw = nthr >> 6;
    if (N > MAXN) N = MAXN;

    if (tid < N) {
        const float* bp = boxes + ((size_t)b * N + tid) * 4;
        float x1 = bp[0], y1 = bp[1], x2 = bp[2], y2 = bp[3];
        sx1[tid] = x1; sy1[tid] = y1; sx2[tid] = x2; sy2[tid] = y2;
        barea[tid] = (x2 - x1) * (y2 - y1);
        blab[tid] = labels[(size_t)b * N + tid];
    }
    __syncthreads();

    // Phase 1: per-prior best object (strict > => first-index ties = argmax).
    // Only 2 live scalars per thread -> no register-array spill.
    for (int p = tid; p < P; p += nthr) {
        float4 pr = ((const float4*)priors)[p];
        float px1 = pr.x - pr.z * 0.5f, py1 = pr.y - pr.w * 0.5f;
        float px2 = pr.x + pr.z * 0.5f, py2 = pr.y + pr.w * 0.5f;
        float parea = (px2 - px1) * (py2 - py1);
        float best = -1.0f; int bestn = 0;
#pragma unroll
        for (int n = 0; n < MAXN; n++) {
            if (n < N) {
                float iw = fmaxf(fminf(sx2[n], px2) - fmaxf(sx1[n], px1), 0.0f);
                float ih = fmaxf(fminf(sy2[n], py2) - fmaxf(sy1[n], py1), 0.0f);
                float inter = iw * ih;
                float iou = inter / (barea[n] + parea - inter);
                if (iou > best) { best = iou; bestn = n; }
            }
        }
        ovl[p] = best;
        obj[p] = (unsigned short)bestn;
    }

    // Phase 2: per-object argmax over priors — wave w handles object w.
    // Lanes scan p ascending (p = lane + i*64); strict > keeps first index
    // per lane; cross-lane reduce prefers larger v, then smaller index.
    for (int n = wid; n < N; n += nw) {
        const float bx1 = sx1[n], by1 = sy1[n], bx2 = sx2[n], by2 = sy2[n];
        const float ba = barea[n];
        float v = -1.0f; int i = 0x7fffffff;
        for (int p = lane; p < P; p += 64) {
            float4 pr = ((const float4*)priors)[p];
            float px1 = pr.x - pr.z * 0.5f, py1 = pr.y - pr.w * 0.5f;
            float px2 = pr.x + pr.z * 0.5f, py2 = pr.y + pr.w * 0.5f;
            float parea = (px2 - px1) * (py2 - py1);
            float iw = fmaxf(fminf(bx2, px2) - fmaxf(bx1, px1), 0.0f);
            float ih = fmaxf(fminf(by2, py2) - fmaxf(by1, py1), 0.0f);
            float inter = iw * ih;
            float iou = inter / (ba + parea - inter);
            if (iou > v) { v = iou; i = p; }
        }
#pragma unroll
        for (int off = 32; off > 0; off >>= 1) {
            float ov = __shfl_down(v, off);
            int   oi = __shfl_down(i, off);
            if (ov > v || (ov == v && oi < i)) { v = ov; i = oi; }
        }
        if (lane == 0) pfo[n] = i;
    }
    __syncthreads();

    // Phase 3: sequential override (last-wins scatter order)
    if (tid == 0) {
        for (int n = 0; n < N; n++) {
            int p = pfo[n];
            obj[p] = (unsigned short)n;
            ovl[p] = 1.0f;
        }
    }
    __syncthreads();

    // Phase 4: labels, gcxgcy encode, SmoothL1, n_pos
    float locs = 0.0f; int np = 0;
    for (int p = tid; p < P; p += nthr) {
        int n = obj[p];
        float ov = ovl[p];
        int lab = (ov < 0.5f) ? 0 : blab[n];
        cls_out[(size_t)b * P + p] = lab;
        if (lab != 0) {
            np++;
            float4 pr = ((const float4*)priors)[p];
            float cx = (sx1[n] + sx2[n]) * 0.5f, cy = (sy1[n] + sy2[n]) * 0.5f;
            float w = sx2[n] - sx1[n], h = sy2[n] - sy1[n];
            float g0 = (cx - pr.x) / (pr.z / 10.0f);
            float g1 = (cy - pr.y) / (pr.w / 10.0f);
            float g2 = logf(w / pr.z) * 5.0f;
            float g3 = logf(h / pr.w) * 5.0f;
            float4 pl = ((const float4*)plocs)[(size_t)b * P + p];
            locs += sl1f(pl.x - g0) + sl1f(pl.y - g1) + sl1f(pl.z - g2) + sl1f(pl.w - g3);
        }
    }
#pragma unroll
    for (int off = 32; off > 0; off >>= 1) {
        locs += __shfl_down(locs, off);
        np   += __shfl_down(np, off);
    }
    if (lane == 0) { redf[wid] = locs; redi[wid] = np; }
    __syncthreads();
    if (tid == 0) {
        float L = 0.0f; int c = 0;
        for (int w = 0; w < nw; w++) { L += redf[w]; c += redi[w]; }
        npos_out[b] = c;
        locsum[b] = L;
    }
}

__global__ __launch_bounds__(256) void k_conf(
    const float* __restrict__ scores, // [total, C]
    int total, int C,
    float* __restrict__ slot,         // in: labels(int), out: conf_neg(float)
    float* __restrict__ possum)       // [gridDim.x]
{
    extern __shared__ float sh[];     // 256*C floats
    __shared__ float redf[4];
    const int tid = threadIdx.x;
    const int lane = tid & 63, wid = tid >> 6;
    const int blk = blockIdx.x;
    const int row0 = blk * 256;

    // Stage 256 rows (256*C floats) coalesced as float4 (total*C % 4 == 0 here).
    const size_t f4base = (size_t)row0 * C / 4;
    const size_t f4total = (size_t)total * C / 4;
    const int f4blk = 64 * C;  // 256*C/4
    const float4* __restrict__ s4 = (const float4*)scores;
    for (int j = tid; j < f4blk; j += 256) {
        size_t g = f4base + j;
        if (g < f4total) ((float4*)sh)[j] = s4[g];
    }
    __syncthreads();

    const int idx = row0 + tid;
    float posc = 0.0f;
    if (idx < total) {
        int lab = ((const int*)slot)[idx];
        const float* r = sh + tid * C;
        float m = -3.402823466e38f;
        for (int c = 0; c < C; c++) m = fmaxf(m, r[c]);
        float sum = 0.0f;
        for (int c = 0; c < C; c++) sum += __expf(r[c] - m);
        float conf = m + __logf(sum) - r[lab];   // -log_softmax[lab]
        if (lab != 0) { posc = conf; conf = 0.0f; }
        slot[idx] = conf;
    }
#pragma unroll
    for (int off = 32; off > 0; off >>= 1) posc += __shfl_down(posc, off);
    if (lane == 0) redf[wid] = posc;
    __syncthreads();
    if (tid == 0) possum[blk] = redf[0] + redf[1] + redf[2] + redf[3];
}

__global__ __launch_bounds__(1024) void k_hard(
    const float* __restrict__ conf,  // [B,P] conf_neg (>=0; 0 at positives)
    const int* __restrict__ npos,
    int P,
    float* __restrict__ hardsum)     // [B]
{
    extern __shared__ unsigned int u[];   // P uints
    __shared__ int   redi[16 * 3];
    __shared__ float redf2[16];
    __shared__ int   redi2[16];
    const int b = blockIdx.x, tid = threadIdx.x;
    const int lane = tid & 63, wid = tid >> 6;
    const int nthr = blockDim.x, nw = nthr >> 6;
    long long kk = (long long)npos[b] * 3;
    int k = kk > P ? P : (int)kk;
    if (k <= 0) {                       // block-uniform; still write partial
        if (tid == 0) hardsum[b] = 0.0f;
        return;
    }

    for (int p = tid; p < P; p += nthr) u[p] = __float_as_uint(conf[(size_t)b * P + p]);
    __syncthreads();

    // Find largest bit pattern t with count(x >= t) >= k (exact k-th largest).
    // 4-ary search: 3 thresholds per round, counts via ballot/popc.
    // Active-lane sets are lane-prefixes (p grows with lane), so lane 0 always
    // sees the last partial iteration and holds the correct wave total.
    unsigned lo = 0u, hi = 0x7F800000u;
    while (lo < hi) {
        unsigned span = hi - lo;
        if (span >= 8) {
            unsigned q = span >> 2;
            unsigned m1 = lo + q, m2 = lo + 2 * q, m3 = lo + 3 * q; // lo<m1<m2<m3<=hi
            int c1 = 0, c2 = 0, c3 = 0;
            for (int p = tid; p < P; p += nthr) {
                unsigned v = u[p];
                c1 += (int)__popcll(__ballot(v >= m1));
                c2 += (int)__popcll(__ballot(v >= m2));
                c3 += (int)__popcll(__ballot(v >= m3));
            }
            if (lane == 0) {
                redi[wid * 3 + 0] = c1; redi[wid * 3 + 1] = c2; redi[wid * 3 + 2] = c3;
            }
            __syncthreads();
            int C1 = 0, C2 = 0, C3 = 0;
            for (int w = 0; w < nw; w++) {
                C1 += redi[w * 3 + 0]; C2 += redi[w * 3 + 1]; C3 += redi[w * 3 + 2];
            }
            __syncthreads();
            if      (C3 >= k) lo = m3;
            else if (C2 >= k) { lo = m2; hi = m3 - 1; }
            else if (C1 >= k) { lo = m1; hi = m2 - 1; }
            else              hi = m1 - 1;
        } else {
            unsigned mid = lo + ((span + 1) >> 1);   // in [lo+1, hi]
            int c = 0;
            for (int p = tid; p < P; p += nthr)
                c += (int)__popcll(__ballot(u[p] >= mid));
            if (lane == 0) redi[wid * 3] = c;
            __syncthreads();
            int Cc = 0;
            for (int w = 0; w < nw; w++) Cc += redi[w * 3];
            __syncthreads();
            if (Cc >= k) lo = mid; else hi = mid - 1;
        }
    }

    float t = __uint_as_float(lo);
    float sgt = 0.0f; int cgt = 0;
    for (int p = tid; p < P; p += nthr) {
        float v = __uint_as_float(u[p]);
        if (v > t) { sgt += v; cgt++; }
    }
#pragma unroll
    for (int off = 32; off > 0; off >>= 1) {
        sgt += __shfl_down(sgt, off);
        cgt += __shfl_down(cgt, off);
    }
    if (lane == 0) { redf2[wid] = sgt; redi2[wid] = cgt; }
    __syncthreads();
    if (tid == 0) {
        float S = 0.0f; int Cg = 0;
        for (int w = 0; w < nw; w++) { S += redf2[w]; Cg += redi2[w]; }
        hardsum[b] = S + (float)(k - Cg) * t;   // ties at t handled exactly
    }
}

__global__ __launch_bounds__(1024) void k_final(
    const int* __restrict__ npos, const float* __restrict__ locsum,
    const float* __restrict__ hardsum, const float* __restrict__ possum,
    int B, int nconf, float* __restrict__ out)
{
    const int tid = threadIdx.x, lane = tid & 63, wid = tid >> 6;
    __shared__ float rf[3 * 16];
    __shared__ int   ri[16];
    float lp = 0, pp = 0, hp = 0; int np = 0;
    for (int i = tid; i < B; i += 1024) { np += npos[i]; lp += locsum[i]; hp += hardsum[i]; }
    for (int i = tid; i < nconf; i += 1024) pp += possum[i];
#pragma unroll
    for (int off = 32; off > 0; off >>= 1) {
        np += __shfl_down(np, off); lp += __shfl_down(lp, off);
        pp += __shfl_down(pp, off); hp += __shfl_down(hp, off);
    }
    if (lane == 0) { ri[wid] = np; rf[wid] = lp; rf[16 + wid] = pp; rf[32 + wid] = hp; }
    __syncthreads();
    if (tid == 0) {
        int nw = (int)(blockDim.x >> 6);
        float L = 0, Pp = 0, H = 0; int Np = 0;
        for (int w = 0; w < nw; w++) { Np += ri[w]; L += rf[w]; Pp += rf[16 + w]; H += rf[32 + w]; }
        float npf = (float)Np;
        out[0] = (H + Pp) / npf + L / (npf * 4.0f);
    }
}

extern "C" void kernel_launch(void* const* d_in, const int* in_sizes, int n_in,
                              void* d_out, int out_size, void* d_ws, size_t ws_size,
                              hipStream_t stream)
{
    const float* plocs  = (const float*)d_in[0];
    const float* scores = (const float*)d_in[1];
    const float* boxes  = (const float*)d_in[2];
    const int*   labels = (const int*)d_in[3];
    const float* priors = (const float*)d_in[4];

    int P = in_sizes[4] / 4;
    int B = in_sizes[0] / (P * 4);
    int C = in_sizes[1] / (in_sizes[0] / 4);
    int N = in_sizes[3] / B;
    int total = B * P;
    int nconf = (total + 255) / 256;

    char* w = (char*)d_ws;
    float* slot    = (float*)w;                 w += (size_t)total * sizeof(float);
    int*   npos    = (int*)w;                   w += (size_t)B * sizeof(int);
    float* locsum  = (float*)w;                 w += (size_t)B * sizeof(float);
    float* hardsum = (float*)w;                 w += (size_t)B * sizeof(float);
    float* possum  = (float*)w;

    size_t sm1 = (size_t)P * (sizeof(float) + sizeof(unsigned short));
    k_match<<<B, 1024, sm1, stream>>>(plocs, boxes, labels, priors, P, N,
                                      (int*)slot, npos, locsum);

    size_t sm2 = (size_t)256 * C * sizeof(float);
    k_conf<<<nconf, 256, sm2, stream>>>(scores, total, C, slot, possum);

    k_hard<<<B, 1024, (size_t)P * sizeof(unsigned int), stream>>>(slot, npos, P, hardsum);

    k_final<<<1, 1024, 0, stream>>>(npos, locsum, hardsum, possum, B, nconf,
                                    (float*)d_out);
}